// Round 1
// baseline (70.934 us; speedup 1.0000x reference)
//
#include <hip/hip_runtime.h>

// QueryAndGroup: ball_query(radius=0.2, nsample=32) + group xyz (centered) + group features.
// B=4, N=16384, M=2048, C=64. Output (B, 3+C, M, 32) float32.
//
// One 64-lane wave per query point. Phase 1: scan xyz in chunks of 64 with
// __ballot; collect first 32 in-radius indices (ascending) into LDS; early-exit.
// Phase 2: gather 67 channels x 32 samples per query (2 channels per iter).

#define WAVES_PER_BLOCK 4

__global__ __launch_bounds__(256) void qg_kernel(
    const float* __restrict__ xyz,      // (B, N, 3)
    const float* __restrict__ new_xyz,  // (B, M, 3)
    const float* __restrict__ feat,     // (B, C, N)
    float* __restrict__ out,            // (B, 3+C, M, 32)
    int B, int N, int M)
{
#pragma clang fp contract(off)
    const int S = 32;          // nsample
    const int C = 64;          // feature channels
    const int lane = threadIdx.x & 63;
    const int wv   = threadIdx.x >> 6;
    const int q    = blockIdx.x * WAVES_PER_BLOCK + wv;  // global query id
    const int b    = q / M;
    const int m    = q % M;

    __shared__ int sidx[WAVES_PER_BLOCK][32];

    const float r2 = 0.2f * 0.2f;
    const float qx = new_xyz[(b * M + m) * 3 + 0];
    const float qy = new_xyz[(b * M + m) * 3 + 1];
    const float qz = new_xyz[(b * M + m) * 3 + 2];

    const float* xb = xyz + (size_t)b * N * 3;

    int count = 0;
    int firstIdx = 0;   // index of first in-radius point (0 if none)
    for (int base = 0; base < N; base += 64) {
        const int i = base + lane;
        const float px = xb[i * 3 + 0];
        const float py = xb[i * 3 + 1];
        const float pz = xb[i * 3 + 2];
        const float dx = qx - px;
        const float dy = qy - py;
        const float dz = qz - pz;
        float d2 = dx * dx + dy * dy;   // ((dx^2+dy^2)+dz^2), no fma: match np/jax f32
        d2 = d2 + dz * dz;
        const bool in = d2 < r2;
        const unsigned long long mask = __ballot(in);
        if (in) {
            const int slot = count + __popcll(mask & ((1ull << lane) - 1ull));
            if (slot < S) sidx[wv][slot] = i;
        }
        if (count == 0 && mask != 0ull)
            firstIdx = base + __builtin_ctzll(mask);
        count += __popcll(mask);
        if (count >= S) break;          // wave-uniform
    }
    // Fill remaining slots with firstIdx (or 0 if no point in radius).
    {
        const int start = count < S ? count : S;
        const int slot = start + lane;
        if (slot < S) sidx[wv][slot] = firstIdx;
    }
    __syncthreads();   // make LDS writes visible across lanes (cheap, uniform)

    // ---- gather phase: 67 channels, 2 per iteration (half-wave each) ----
    const int s     = lane & 31;
    const int chalf = lane >> 5;
    const int myid  = sidx[wv][s];

    const float* fb = feat + (size_t)b * C * N;
    const size_t obase = ((size_t)b * (3 + C) * M + m) * S;  // out[b][0][m][0]

    const float cx = qx, cy = qy, cz = qz;

    #pragma unroll 4
    for (int it = 0; it < (3 + C + 1) / 2; ++it) {
        const int c = it * 2 + chalf;
        if (c < 3 + C) {
            float v;
            if (c < 3) {
                const float p = xb[myid * 3 + c];
                const float ctr = (c == 0) ? cx : (c == 1) ? cy : cz;
                v = p - ctr;
            } else {
                v = fb[(size_t)(c - 3) * N + myid];
            }
            out[obase + (size_t)c * M * S + s] = v;
        }
    }
}

extern "C" void kernel_launch(void* const* d_in, const int* in_sizes, int n_in,
                              void* d_out, int out_size, void* d_ws, size_t ws_size,
                              hipStream_t stream) {
    const float* xyz     = (const float*)d_in[0];
    const float* new_xyz = (const float*)d_in[1];
    const float* feat    = (const float*)d_in[2];
    float* out           = (float*)d_out;

    const int B = 4, N = 16384, M = 2048;

    dim3 grid((B * M) / WAVES_PER_BLOCK);
    dim3 block(WAVES_PER_BLOCK * 64);
    hipLaunchKernelGGL(qg_kernel, grid, block, 0, stream,
                       xyz, new_xyz, feat, out, B, N, M);
}

// Round 2
// 38.883 us; speedup vs baseline: 1.8243x; 1.8243x over previous
//
#include <hip/hip_runtime.h>

// QueryAndGroup: ball_query(r=0.2, nsample=32) + group xyz (centered) + group features.
// B=4, N=16384, M=2048, C=64. Output (B, 67, M, 32) f32.
//
// Kernel 1: transpose feat (B,C,N) -> featT (B,N,C) in d_ws, so the per-sample
//           gather reads a contiguous 256B row (2 cache lines) instead of 67
//           scattered 4B touches 64KB apart (~30x less L2 traffic).
// Kernel 2: one wave per query. Scan xyz in 256-point groups (4x64 chunks,
//           loads batched -> one load-latency per group) collecting first 32
//           in-radius indices via ballot/prefix-popcount; then float4 gather
//           from featT with s-coalesced stores.

#define WPB 4
constexpr int Bc = 4, Nc = 16384, Mc = 2048, Cc = 64, Sc = 32;

__global__ __launch_bounds__(256) void transpose_kernel(
    const float* __restrict__ feat,  // (B, C, N)
    float* __restrict__ featT)       // (B, N, C)
{
    __shared__ float tile[64][65];
    const int b = blockIdx.y;
    const int nbase = blockIdx.x * 64;
    const int tid = threadIdx.x;
    const int tn = tid & 63;
    const int tq = tid >> 6;  // 0..3
    const float* fb = feat + (size_t)b * Cc * Nc;
    float* ob = featT + (size_t)b * Nc * Cc;
    #pragma unroll
    for (int k = 0; k < 16; ++k) {
        const int c = k * 4 + tq;
        tile[tn][c] = fb[(size_t)c * Nc + nbase + tn];   // coalesced 256B reads
    }
    __syncthreads();
    #pragma unroll
    for (int k = 0; k < 16; ++k) {
        const int nl = k * 4 + tq;
        ob[(size_t)(nbase + nl) * Cc + tn] = tile[nl][tn];  // coalesced 256B writes
    }
}

__global__ __launch_bounds__(256) void qg_kernel(
    const float* __restrict__ xyz,      // (B, N, 3)
    const float* __restrict__ new_xyz,  // (B, M, 3)
    const float* __restrict__ feat,     // (B, C, N)
    const float* __restrict__ featT,    // (B, N, C) or garbage if useT==0
    float* __restrict__ out,            // (B, 67, M, 32)
    int useT)
{
#pragma clang fp contract(off)
    const int lane = threadIdx.x & 63;
    const int wv   = threadIdx.x >> 6;
    const int q    = blockIdx.x * WPB + wv;
    const int b    = q >> 11;          // / Mc
    const int m    = q & (Mc - 1);

    __shared__ int sidx[WPB][Sc];

    const float r2 = 0.2f * 0.2f;
    const float* nz = new_xyz + (size_t)(b * Mc + m) * 3;
    const float qx = nz[0], qy = nz[1], qz = nz[2];
    const float* xb = xyz + (size_t)b * Nc * 3;

    int count = 0, firstIdx = 0;
    const unsigned long long lt = (1ull << lane) - 1ull;
    for (int base = 0; base < Nc; base += 256) {
        float px[4], py[4], pz[4];
        #pragma unroll
        for (int u = 0; u < 4; ++u) {           // batch 12 loads: 1 latency / 256 pts
            const float* pp = xb + (size_t)(base + u * 64 + lane) * 3;
            px[u] = pp[0]; py[u] = pp[1]; pz[u] = pp[2];
        }
        #pragma unroll
        for (int u = 0; u < 4; ++u) {
            const float dx = qx - px[u], dy = qy - py[u], dz = qz - pz[u];
            float d2 = dx * dx + dy * dy;       // no fma: match np/jax f32 rounding
            d2 = d2 + dz * dz;
            const bool in = d2 < r2;
            const unsigned long long mask = __ballot(in);
            if (in) {
                const int slot = count + __popcll(mask & lt);
                if (slot < Sc) sidx[wv][slot] = base + u * 64 + lane;
            }
            if (count == 0 && mask != 0ull)
                firstIdx = base + u * 64 + __builtin_ctzll(mask);
            count += __popcll(mask);
        }
        if (count >= Sc) break;                 // wave-uniform
    }
    {
        const int start = count < Sc ? count : Sc;
        if (start + lane < Sc) sidx[wv][start + lane] = firstIdx;
    }
    // Same-wave LDS visibility only; avoids coupling the 4 waves' scan lengths.
    asm volatile("s_waitcnt lgkmcnt(0)" ::: "memory");

    const int s     = lane & 31;
    const int chalf = lane >> 5;
    const int myid  = sidx[wv][s];
    float* ob = out + ((size_t)b * 67 * Mc + m) * Sc;

    // xyz channels 0..2 (centered)
    #pragma unroll
    for (int it = 0; it < 2; ++it) {
        const int c = it * 2 + chalf;
        if (c < 3) {
            const float ctr = (c == 0) ? qx : (c == 1) ? qy : qz;
            ob[(size_t)c * (Mc * Sc) + s] = xb[(size_t)myid * 3 + c] - ctr;
        }
    }

    if (useT) {
        // 256B-aligned row of 64 channels for this sample: 8 float4 loads/lane.
        const float* ftb = featT + ((size_t)b * Nc + myid) * Cc;
        #pragma unroll
        for (int it = 0; it < 8; ++it) {
            const int c4 = it * 2 + chalf;                 // 0..15
            const float4 v = *(const float4*)(ftb + (size_t)c4 * 4);
            #pragma unroll
            for (int k = 0; k < 4; ++k)
                ob[(size_t)(3 + c4 * 4 + k) * (Mc * Sc) + s] = ((const float*)&v)[k];
        }
    } else {
        // Fallback: direct (C,N) gather.
        const float* fb = feat + (size_t)b * Cc * Nc;
        #pragma unroll
        for (int it = 0; it < 32; ++it) {
            const int c = it * 2 + chalf;
            ob[(size_t)(3 + c) * (Mc * Sc) + s] = fb[(size_t)c * Nc + myid];
        }
    }
}

extern "C" void kernel_launch(void* const* d_in, const int* in_sizes, int n_in,
                              void* d_out, int out_size, void* d_ws, size_t ws_size,
                              hipStream_t stream) {
    const float* xyz     = (const float*)d_in[0];
    const float* new_xyz = (const float*)d_in[1];
    const float* feat    = (const float*)d_in[2];
    float* out           = (float*)d_out;

    const size_t needT = (size_t)Bc * Nc * Cc * sizeof(float);  // 16.8 MB
    float* featT = (float*)d_ws;
    const int useT = (ws_size >= needT) ? 1 : 0;

    if (useT) {
        dim3 g(Nc / 64, Bc);
        hipLaunchKernelGGL(transpose_kernel, g, dim3(256), 0, stream, feat, featT);
    }
    hipLaunchKernelGGL(qg_kernel, dim3((Bc * Mc) / WPB), dim3(256), 0, stream,
                       xyz, new_xyz, feat, featT, out, useT);
}